// Round 7
// baseline (111.744 us; speedup 1.0000x reference)
//
#include <hip/hip_runtime.h>

// PositionalEmbedding: out[node, t*32 + j] = (child_pos(ancestor_t(node)) == j)
// N = 262144, n = 32, k = 16. Output float32 [N, 512] = 512 MiB, write-BW-bound.
// R7: R6 (load-free readlane store loop) + nontemporal stores.
// Isolated A/B: only the store cache-policy bit changes vs R6 (111.3 us).

#define NN 32   // one-hot width (n)
#define KK 16   // ancestor depth (k)

typedef float f32x4 __attribute__((ext_vector_type(4)));

__global__ __launch_bounds__(256) void pe_fused_rl(
    const int* __restrict__ parents,
    const int* __restrict__ child_pos,
    f32x4* __restrict__ out4, int N)
{
    const int lane  = (int)(threadIdx.x & 63);
    const int wid   = (int)((blockIdx.x * blockDim.x + threadIdx.x) >> 6);
    const int wbase = wid * 64;          // first node-row of this wave
    const int node  = wbase + lane;      // this lane chases this node

    // ---- Phase A: per-lane 16-step ancestor chase -> 4 packed dwords ----
    unsigned int c[4];
    {
        int cur = (node < N) ? node : N;
        #pragma unroll
        for (int w = 0; w < 4; ++w) {
            unsigned int u = 0;
            #pragma unroll
            for (int b = 0; b < 4; ++b) {
                const int cp = child_pos[cur];               // independent
                const unsigned int byte = (cp < NN) ? (unsigned int)cp : 0xFFu;
                u |= byte << (8 * b);
                cur = parents[cur];                          // dependent chain
            }
            c[w] = u;
        }
    }

    // ---- Phase B: wait-free store loop over the wave's 64 rows ----
    const bool hi32 = (lane >= 32);
    const int  sh   = ((lane >> 3) & 3) * 8;   // byte-in-dword shift
    const int  q4   = (lane & 7) * 4;          // one-hot quad base

    f32x4* wout = out4 + (size_t)wbase * 128 + lane;

    #pragma unroll 4
    for (int r = 0; r < 64; ++r) {
        const unsigned s0 = (unsigned)__builtin_amdgcn_readlane((int)c[0], r);
        const unsigned s1 = (unsigned)__builtin_amdgcn_readlane((int)c[1], r);
        const unsigned s2 = (unsigned)__builtin_amdgcn_readlane((int)c[2], r);
        const unsigned s3 = (unsigned)__builtin_amdgcn_readlane((int)c[3], r);

        const int code0 = (int)(((hi32 ? s1 : s0) >> sh) & 0xFFu);
        const int code1 = (int)(((hi32 ? s3 : s2) >> sh) & 0xFFu);

        f32x4 v0, v1;
        v0.x = (code0 == q4    ) ? 1.0f : 0.0f;
        v0.y = (code0 == q4 + 1) ? 1.0f : 0.0f;
        v0.z = (code0 == q4 + 2) ? 1.0f : 0.0f;
        v0.w = (code0 == q4 + 3) ? 1.0f : 0.0f;
        v1.x = (code1 == q4    ) ? 1.0f : 0.0f;
        v1.y = (code1 == q4 + 1) ? 1.0f : 0.0f;
        v1.z = (code1 == q4 + 2) ? 1.0f : 0.0f;
        v1.w = (code1 == q4 + 3) ? 1.0f : 0.0f;

        __builtin_nontemporal_store(v0, &wout[(size_t)r * 128]);
        __builtin_nontemporal_store(v1, &wout[(size_t)r * 128 + 64]);
    }
}

extern "C" void kernel_launch(void* const* d_in, const int* in_sizes, int n_in,
                              void* d_out, int out_size, void* d_ws, size_t ws_size,
                              hipStream_t stream) {
    const int* parents   = (const int*)d_in[0];
    const int* child_pos = (const int*)d_in[1];
    f32x4* out4 = (f32x4*)d_out;

    const int N = in_sizes[0] - 1;                 // 262144
    const int n_waves = (N + 63) / 64;             // 4096 waves
    const int grid    = (n_waves + 3) / 4;         // 1024 blocks

    pe_fused_rl<<<grid, 256, 0, stream>>>(parents, child_pos, out4, N);
}